// Round 1
// baseline (60.995 us; speedup 1.0000x reference)
//
#include <hip/hip_runtime.h>
#include <math.h>

// RobustListLearner: for each (feature-pair f, sample-pair s) solve
// w = pinv(A) @ y for a 2x2 system. See theory above.
//
// Sizes (fixed by the reference): N=96, D=64, k=2
//   Ms = C(96,2) = 4560, Mf = C(64,2) = 2016, total M = 9,192,960 rows.
// Output buffer: [weights: M*2 f32][col_indices: M*2 written as f32 values]

#define MS 4560
#define MF 2016
#define TOTAL (MS * MF)          // 9,192,960
#define MARGIN 0.1
// jax pinv default rcond = 10 * max(M,N) * eps_f32 = 20 * 2^-23
#define RCOND 2.384185791015625e-06

__global__ __launch_bounds__(256) void rll_kernel(
    const float* __restrict__ labels,     // [96]
    const float* __restrict__ features,   // [96][64]
    const int*   __restrict__ sample_idx, // [4560][2]
    const int*   __restrict__ feat_idx,   // [2016][2]
    float* __restrict__ w_out,            // [TOTAL][2]
    float* __restrict__ c_out)            // [TOTAL][2] (float-encoded ints)
{
    unsigned m = blockIdx.x * blockDim.x + threadIdx.x;
    if (m >= TOTAL) return;
    unsigned f = m / MS;          // feature-pair index (magic-mul div)
    unsigned s = m - f * MS;      // sample-pair index

    int i = sample_idx[2 * s];
    int j = sample_idx[2 * s + 1];
    int a = feat_idx[2 * f];
    int b = feat_idx[2 * f + 1];

    double li = (double)labels[i];
    double lj = (double)labels[j];
    double A00 = li * (double)features[i * 64 + a];
    double A01 = li * (double)features[i * 64 + b];
    double A10 = lj * (double)features[j * 64 + a];
    double A11 = lj * (double)features[j * 64 + b];
    double y0 = li - MARGIN;
    double y1 = lj - MARGIN;

    // Closed-form 2x2 singular values:
    //   E=(a+d)/2 F=(a-d)/2 G=(c+b)/2 H=(c-b)/2
    //   Q=sqrt(E^2+H^2) R=sqrt(F^2+G^2); s1=Q+R, s2=|Q-R|
    double E = 0.5 * (A00 + A11);
    double F = 0.5 * (A00 - A11);
    double G = 0.5 * (A10 + A01);
    double H = 0.5 * (A10 - A01);
    double Q = sqrt(E * E + H * H);
    double R = sqrt(F * F + G * G);
    double s1 = Q + R;
    double s2 = fabs(Q - R);

    double w0, w1;
    if (s2 > RCOND * s1) {
        // full-rank: exact 2x2 inverse
        double det = A00 * A11 - A01 * A10;
        double inv = 1.0 / det;
        w0 = (A11 * y0 - A01 * y1) * inv;
        w1 = (A00 * y1 - A10 * y0) * inv;
    } else {
        // rank<=1: truncated pinv ~= A^T y / ||A||_F^2
        // (rel. error O(s2/s1) <= rcond vs exact truncated SVD)
        double fr = A00 * A00 + A01 * A01 + A10 * A10 + A11 * A11;
        if (fr > 0.0) {
            double invf = 1.0 / fr;
            w0 = (A00 * y0 + A10 * y1) * invf;
            w1 = (A01 * y0 + A11 * y1) * invf;
        } else {
            w0 = 0.0;
            w1 = 0.0;
        }
    }

    ((float2*)w_out)[m] = make_float2((float)w0, (float)w1);
    ((float2*)c_out)[m] = make_float2((float)a, (float)b);
}

extern "C" void kernel_launch(void* const* d_in, const int* in_sizes, int n_in,
                              void* d_out, int out_size, void* d_ws, size_t ws_size,
                              hipStream_t stream) {
    const float* labels     = (const float*)d_in[0];
    const float* features   = (const float*)d_in[1];
    const int*   sample_idx = (const int*)d_in[2];
    const int*   feat_idx   = (const int*)d_in[3];

    float* w_out = (float*)d_out;                       // TOTAL*2 floats
    float* c_out = (float*)d_out + (size_t)TOTAL * 2;   // TOTAL*2 floats

    const int block = 256;
    const int grid = (TOTAL + block - 1) / block;       // 35910 exactly
    rll_kernel<<<grid, block, 0, stream>>>(labels, features, sample_idx,
                                           feat_idx, w_out, c_out);
}

// Round 2
// 60.665 us; speedup vs baseline: 1.0054x; 1.0054x over previous
//
#include <hip/hip_runtime.h>
#include <math.h>

// RobustListLearner: for each (feature-pair f, sample-pair s) solve
// w = pinv(A) @ y for a 2x2 system, closed form.
//
// N=96, D=64, k=2 -> Ms=C(96,2)=4560, Mf=C(64,2)=2016, M=9,192,960 rows.
// Output: [weights: M*2 f32][col_indices: M*2 as f32 values].
//
// Numerics (why no sqrt / no f64 div is safe):
//  - A[r][c] = label*feature is EXACT in f32; f64 products of f32 are exact,
//    so det (one f64 subtract of exact products) is correctly rounded.
//  - s1*s2 = |det|, s1^2+s2^2 = frob^2  =>  (s2 > rc*s1) <=> det^2 > rc^2*s1^4,
//    and s1^4 = fr^2*(1-O(rc^2)) near the cutoff  =>  test det^2 > rc^2*fr^2.
//    Decision shift vs the sqrt form: ~1e-11 relative. Same flips as before.
//  - Final divide in f32: adds <=1.2e-7 relative to w (<=0.1 abs at |w|~7e5),
//    threshold is 1.44e4.

#define MS 4560
#define MF 2016
#define TOTAL (MS * MF)          // 9,192,960
#define MARGIN 0.1
// jax pinv rcond = 10 * max(M,N) * eps_f32 = 20 * 2^-23
#define RCOND 2.384185791015625e-06
#define RC2 (RCOND * RCOND)

__global__ __launch_bounds__(256) void rll_kernel(
    const float* __restrict__ labels,     // [96]
    const float* __restrict__ features,   // [96][64]
    const int*   __restrict__ sample_idx, // [4560][2]
    const int*   __restrict__ feat_idx,   // [2016][2]
    float* __restrict__ w_out,            // [TOTAL][2]
    float* __restrict__ c_out)            // [TOTAL][2] (float-encoded ints)
{
    unsigned m = blockIdx.x * blockDim.x + threadIdx.x;
    if (m >= TOTAL) return;
    unsigned f = m / MS;          // feature-pair index (magic-mul div)
    unsigned s = m - f * MS;      // sample-pair index

    int2 ij = ((const int2*)sample_idx)[s];
    int2 ab = ((const int2*)feat_idx)[f];

    float li = labels[ij.x];
    float lj = labels[ij.y];
    // exact in f32 (label is +-1)
    float a00 = li * features[ij.x * 64 + ab.x];
    float a01 = li * features[ij.x * 64 + ab.y];
    float a10 = lj * features[ij.y * 64 + ab.x];
    float a11 = lj * features[ij.y * 64 + ab.y];

    double dA00 = (double)a00, dA01 = (double)a01;
    double dA10 = (double)a10, dA11 = (double)a11;

    // exact products -> det correctly rounded in f64
    double det = dA00 * dA11 - dA01 * dA10;
    double fr  = dA00 * dA00 + dA01 * dA01 + dA10 * dA10 + dA11 * dA11;

    double y0 = (double)li - MARGIN;
    double y1 = (double)lj - MARGIN;

    float w0, w1;
    if (det * det > RC2 * (fr * fr)) {
        // full-rank: exact 2x2 inverse; numerators in f64, divide in f32
        double num0 = dA11 * y0 - dA01 * y1;
        double num1 = dA00 * y1 - dA10 * y0;
        float rd = 1.0f / (float)det;
        w0 = (float)num0 * rd;
        w1 = (float)num1 * rd;
    } else {
        // rank<=1: truncated pinv ~= A^T y / ||A||_F^2 (rare path, f32 ok:
        // values are O(1), rel error O(rc) vs exact truncated SVD)
        float frf = (float)fr;
        if (frf > 0.0f) {
            float rf = 1.0f / frf;
            float fy0 = li - 0.1f, fy1 = lj - 0.1f;
            w0 = (a00 * fy0 + a10 * fy1) * rf;
            w1 = (a01 * fy0 + a11 * fy1) * rf;
        } else {
            w0 = 0.0f;
            w1 = 0.0f;
        }
    }

    ((float2*)w_out)[m] = make_float2(w0, w1);
    ((float2*)c_out)[m] = make_float2((float)ab.x, (float)ab.y);
}

extern "C" void kernel_launch(void* const* d_in, const int* in_sizes, int n_in,
                              void* d_out, int out_size, void* d_ws, size_t ws_size,
                              hipStream_t stream) {
    const float* labels     = (const float*)d_in[0];
    const float* features   = (const float*)d_in[1];
    const int*   sample_idx = (const int*)d_in[2];
    const int*   feat_idx   = (const int*)d_in[3];

    float* w_out = (float*)d_out;                       // TOTAL*2 floats
    float* c_out = (float*)d_out + (size_t)TOTAL * 2;   // TOTAL*2 floats

    const int block = 256;
    const int grid = (TOTAL + block - 1) / block;       // 35910 exactly
    rll_kernel<<<grid, block, 0, stream>>>(labels, features, sample_idx,
                                           feat_idx, w_out, c_out);
}

// Round 3
// 39.025 us; speedup vs baseline: 1.5630x; 1.5545x over previous
//
#include <hip/hip_runtime.h>
#include <math.h>

// RobustListLearner: for each (feature-pair f, sample-pair s) solve
// w = pinv(A) @ y for a 2x2 system, closed form.
//
// N=96, D=64, k=2 -> Ms=C(96,2)=4560, Mf=C(64,2)=2016, M=9,192,960 rows.
// Output: [weights: M*2 f32][col_indices: M*2 as f32 values].
//
// Memory layout insight (round 2 post-mortem): within a wave, f (and i,
// mostly) are uniform while j increments per lane. Reading the row-major
// features[j*64+a] gathers 64 distinct 256B-strided lines per wave -> L1
// transaction-bound (~60us). We pre-transpose labels*features into
// lfT[feature][sample] (24 KB in d_ws) so every access is either
// wave-uniform (broadcast) or lane-consecutive (coalesced).
//
// Numerics (unchanged from the passing round-2 kernel):
//  - A[r][c] = label*feature is EXACT in f32; f64 products of f32 are exact,
//    so det (one f64 subtract of exact products) is correctly rounded.
//  - s1*s2 = |det|, s1^2+s2^2 = fr  =>  (s2 > rc*s1) <=> det^2 > rc^2*s1^4,
//    s1^4 = fr^2*(1-O(rc^2)) near the cutoff  =>  test det^2 > rc^2*fr^2.
//  - Final divide in f32: rel err ~1.2e-7 (<=0.1 abs at |w|~7e5 vs 1.44e4).

#define NSAMP 96
#define NFEAT 64
#define MS 4560
#define MF 2016
#define TOTAL (MS * MF)          // 9,192,960
#define MARGIN 0.1
// jax pinv rcond = 10 * max(M,N) * eps_f32 = 20 * 2^-23
#define RCOND 2.384185791015625e-06
#define RC2 (RCOND * RCOND)

// lfT[a*96 + i] = labels[i] * features[i*64 + a]   (24 KB)
__global__ __launch_bounds__(256) void prep_kernel(
    const float* __restrict__ labels,
    const float* __restrict__ features,
    float* __restrict__ lfT)
{
    int t = blockIdx.x * blockDim.x + threadIdx.x;
    if (t >= NSAMP * NFEAT) return;
    int a = t / NSAMP;   // feature index
    int i = t - a * NSAMP; // sample index
    lfT[t] = labels[i] * features[i * NFEAT + a];
}

__global__ __launch_bounds__(256) void rll_kernel(
    const float* __restrict__ labels,     // [96]
    const float* __restrict__ lfT,        // [64][96] transposed label*feature
    const int*   __restrict__ sample_idx, // [4560][2]
    const int*   __restrict__ feat_idx,   // [2016][2]
    float* __restrict__ w_out,            // [TOTAL][2]
    float* __restrict__ c_out)            // [TOTAL][2] (float-encoded ints)
{
    unsigned m = blockIdx.x * blockDim.x + threadIdx.x;
    if (m >= TOTAL) return;
    unsigned f = m / MS;          // feature-pair index (uniform per block)
    unsigned s = m - f * MS;      // sample-pair index (lane-consecutive)

    int2 ij = ((const int2*)sample_idx)[s];   // i uniform-ish, j consecutive
    int2 ab = ((const int2*)feat_idx)[f];     // uniform

    // all four loads: wave-uniform (i) or lane-consecutive (j) -> 1-2 lines
    float a00 = lfT[ab.x * NSAMP + ij.x];
    float a01 = lfT[ab.y * NSAMP + ij.x];
    float a10 = lfT[ab.x * NSAMP + ij.y];
    float a11 = lfT[ab.y * NSAMP + ij.y];
    float li = labels[ij.x];
    float lj = labels[ij.y];

    double dA00 = (double)a00, dA01 = (double)a01;
    double dA10 = (double)a10, dA11 = (double)a11;

    // exact products -> det correctly rounded in f64
    double det = dA00 * dA11 - dA01 * dA10;
    double fr  = dA00 * dA00 + dA01 * dA01 + dA10 * dA10 + dA11 * dA11;

    double y0 = (double)li - MARGIN;
    double y1 = (double)lj - MARGIN;

    float w0, w1;
    if (det * det > RC2 * (fr * fr)) {
        // full-rank: exact 2x2 inverse; numerators in f64, divide in f32
        double num0 = dA11 * y0 - dA01 * y1;
        double num1 = dA00 * y1 - dA10 * y0;
        float rd = 1.0f / (float)det;
        w0 = (float)num0 * rd;
        w1 = (float)num1 * rd;
    } else {
        // rank<=1: truncated pinv ~= A^T y / ||A||_F^2 (rare path)
        float frf = (float)fr;
        if (frf > 0.0f) {
            float rf = 1.0f / frf;
            float fy0 = li - 0.1f, fy1 = lj - 0.1f;
            w0 = (a00 * fy0 + a10 * fy1) * rf;
            w1 = (a01 * fy0 + a11 * fy1) * rf;
        } else {
            w0 = 0.0f;
            w1 = 0.0f;
        }
    }

    ((float2*)w_out)[m] = make_float2(w0, w1);
    ((float2*)c_out)[m] = make_float2((float)ab.x, (float)ab.y);
}

extern "C" void kernel_launch(void* const* d_in, const int* in_sizes, int n_in,
                              void* d_out, int out_size, void* d_ws, size_t ws_size,
                              hipStream_t stream) {
    const float* labels     = (const float*)d_in[0];
    const float* features   = (const float*)d_in[1];
    const int*   sample_idx = (const int*)d_in[2];
    const int*   feat_idx   = (const int*)d_in[3];

    float* lfT   = (float*)d_ws;                        // 24 KB scratch
    float* w_out = (float*)d_out;                       // TOTAL*2 floats
    float* c_out = (float*)d_out + (size_t)TOTAL * 2;   // TOTAL*2 floats

    prep_kernel<<<(NSAMP * NFEAT + 255) / 256, 256, 0, stream>>>(
        labels, features, lfT);

    const int block = 256;
    const int grid = (TOTAL + block - 1) / block;       // 35910 exactly
    rll_kernel<<<grid, block, 0, stream>>>(labels, lfT, sample_idx,
                                           feat_idx, w_out, c_out);
}

// Round 5
// 37.671 us; speedup vs baseline: 1.6191x; 1.0359x over previous
//
#include <hip/hip_runtime.h>
#include <math.h>

// RobustListLearner: for each (feature-pair f, sample-pair s) solve
// w = pinv(A) @ y for a 2x2 system, closed form.
//
// N=96, D=64, k=2 -> Ms=C(96,2)=4560, Mf=C(64,2)=2016, M=9,192,960 rows.
// Output: [weights: M*2 f32][col_indices: M*2 as f32 values].
//
// Round-3 result: lfT transpose fixed the gather bottleneck (60.7->39.0us).
// Round-5: 2 outputs/thread + float4 nontemporal stores (via native clang
// vector type — HIP float4 is a class and rejected by the builtin),
// f = blockIdx.y (block-uniform -> no magic-div, scalar feat_idx load,
// SGPR row bases). Per-output math bit-identical to round 3.
//
// Numerics:
//  - A[r][c] = label*feature EXACT in f32; f64 products of f32 exact ->
//    det correctly rounded.
//  - (s2 > rc*s1) <=> det^2 > rc^2*s1^4 ; s1^4 = fr^2(1-O(rc^2)) near cutoff
//    => test det^2 > rc^2*fr^2.
//  - Final divide f32: rel err ~1.2e-7 (<=0.1 abs at |w|~7e5 vs 1.44e4 thr).

#define NSAMP 96
#define NFEAT 64
#define MS 4560
#define MF 2016
#define TOTAL (MS * MF)          // 9,192,960
#define MARGIN 0.1
// jax pinv rcond = 10 * max(M,N) * eps_f32 = 20 * 2^-23
#define RCOND 2.384185791015625e-06
#define RC2 (RCOND * RCOND)

typedef float f32x4 __attribute__((ext_vector_type(4)));

// lfT[a*96 + i] = labels[i] * features[i*64 + a]   (24 KB)
__global__ __launch_bounds__(256) void prep_kernel(
    const float* __restrict__ labels,
    const float* __restrict__ features,
    float* __restrict__ lfT)
{
    int t = blockIdx.x * blockDim.x + threadIdx.x;
    if (t >= NSAMP * NFEAT) return;
    int a = t / NSAMP;     // feature index
    int i = t - a * NSAMP; // sample index
    lfT[t] = labels[i] * features[i * NFEAT + a];
}

__device__ __forceinline__ void solve2x2(
    float a00, float a01, float a10, float a11,
    float li, float lj, float& w0, float& w1)
{
    double dA00 = (double)a00, dA01 = (double)a01;
    double dA10 = (double)a10, dA11 = (double)a11;

    // exact products -> det correctly rounded in f64
    double det = dA00 * dA11 - dA01 * dA10;
    double fr  = dA00 * dA00 + dA01 * dA01 + dA10 * dA10 + dA11 * dA11;

    double y0 = (double)li - MARGIN;
    double y1 = (double)lj - MARGIN;

    if (det * det > RC2 * (fr * fr)) {
        // full-rank: exact 2x2 inverse; numerators f64, divide f32
        double num0 = dA11 * y0 - dA01 * y1;
        double num1 = dA00 * y1 - dA10 * y0;
        float rd = 1.0f / (float)det;
        w0 = (float)num0 * rd;
        w1 = (float)num1 * rd;
    } else {
        // rank<=1: truncated pinv ~= A^T y / ||A||_F^2 (rare path)
        float frf = (float)fr;
        if (frf > 0.0f) {
            float rf = 1.0f / frf;
            float fy0 = li - 0.1f, fy1 = lj - 0.1f;
            w0 = (a00 * fy0 + a10 * fy1) * rf;
            w1 = (a01 * fy0 + a11 * fy1) * rf;
        } else {
            w0 = 0.0f;
            w1 = 0.0f;
        }
    }
}

// grid: (ceil(2280/256)=9, 2016); each thread does sample-pairs s0=2t, 2t+1
// for feature-pair f=blockIdx.y, writing one float4 per output stream.
__global__ __launch_bounds__(256) void rll_kernel(
    const float* __restrict__ labels,     // [96]
    const float* __restrict__ lfT,        // [64][96] transposed label*feature
    const int*   __restrict__ sample_idx, // [4560][2]
    const int*   __restrict__ feat_idx,   // [2016][2]
    float* __restrict__ w_out,            // [TOTAL][2]
    float* __restrict__ c_out)            // [TOTAL][2] (float-encoded ints)
{
    int t = blockIdx.x * blockDim.x + threadIdx.x;   // pair-of-pairs index
    if (t >= MS / 2) return;                          // 2280 threads per f
    int f = blockIdx.y;                               // block-uniform

    int2 ab = ((const int2*)feat_idx)[f];             // scalar load
    const float* __restrict__ rowA = lfT + ab.x * NSAMP;  // SGPR base
    const float* __restrict__ rowB = lfT + ab.y * NSAMP;

    // sample pairs s0=2t and s0+1: one 16B load
    int4 ss = ((const int4*)sample_idx)[t];           // (i0,j0,i1,j1)

    // pair 0
    float li0 = labels[ss.x], lj0 = labels[ss.y];
    float w00, w01;
    solve2x2(rowA[ss.x], rowB[ss.x], rowA[ss.y], rowB[ss.y], li0, lj0, w00, w01);
    // pair 1
    float li1 = labels[ss.z], lj1 = labels[ss.w];
    float w10, w11;
    solve2x2(rowA[ss.z], rowB[ss.z], rowA[ss.w], rowB[ss.w], li1, lj1, w10, w11);

    size_t q = (size_t)f * (MS / 2) + t;              // float4 index
    f32x4 wv = { w00, w01, w10, w11 };
    __builtin_nontemporal_store(wv, (f32x4*)w_out + q);
    float af = (float)ab.x, bf = (float)ab.y;
    f32x4 cv = { af, bf, af, bf };
    __builtin_nontemporal_store(cv, (f32x4*)c_out + q);
}

extern "C" void kernel_launch(void* const* d_in, const int* in_sizes, int n_in,
                              void* d_out, int out_size, void* d_ws, size_t ws_size,
                              hipStream_t stream) {
    const float* labels     = (const float*)d_in[0];
    const float* features   = (const float*)d_in[1];
    const int*   sample_idx = (const int*)d_in[2];
    const int*   feat_idx   = (const int*)d_in[3];

    float* lfT   = (float*)d_ws;                        // 24 KB scratch
    float* w_out = (float*)d_out;                       // TOTAL*2 floats
    float* c_out = (float*)d_out + (size_t)TOTAL * 2;   // TOTAL*2 floats

    prep_kernel<<<(NSAMP * NFEAT + 255) / 256, 256, 0, stream>>>(
        labels, features, lfT);

    dim3 grid((MS / 2 + 255) / 256, MF);                // (9, 2016)
    rll_kernel<<<grid, 256, 0, stream>>>(labels, lfT, sample_idx,
                                         feat_idx, w_out, c_out);
}

// Round 6
// 35.696 us; speedup vs baseline: 1.7087x; 1.0553x over previous
//
#include <hip/hip_runtime.h>
#include <math.h>

// RobustListLearner: for each (feature-pair f, sample-pair s) solve
// w = pinv(A) @ y for a 2x2 system, closed form.
//
// N=96, D=64, k=2 -> Ms=C(96,2)=4560, Mf=C(64,2)=2016, M=9,192,960 rows.
// Output: [weights: M*2 f32][col_indices: M*2 as f32 values].
//
// Ladder: 61us (naive) -> 39us (lfT transpose kills strided gather)
// -> 37.7us (float4 nt stores, blockIdx.y=f). Round 6: f64 was co-dominant
// with stores (~224 cy/wave vs 197); go all-f32 on the common path:
//  - Kahan-fma determinant: <=2ulp rel error even under cancellation
//    -> weight error <= ~0.35 abs (threshold 1.44e4).
//  - Rank decision: f32 test can only disagree with the f64 test within
//    +-14eps (~1.7e-6) relative of the cutoff (detk^2 rel<=5eps,
//    RC2F*fr^2 rel<=9eps, RC2 exactly representable in f32). Outside a
//    +-1e-5 band decide in f32; inside, recompute the EXACT f64 test of
//    the passing rounds 1-5 (rare: ~handful of lanes in 9.2M).
//    => decisions provably bit-identical to the passing kernel.

#define NSAMP 96
#define NFEAT 64
#define MS 4560
#define MF 2016
#define TOTAL (MS * MF)          // 9,192,960
// jax pinv rcond = 10 * max(M,N) * eps_f32 = 20 * 2^-23
#define RCOND 2.384185791015625e-06
#define RC2 (RCOND * RCOND)      // 25*2^-42: exactly representable in f32
#define RC2F ((float)RC2)
#define BANDHI 1.00001f
#define BANDLO 0.99999f

typedef float f32x4 __attribute__((ext_vector_type(4)));

// lfT[a*96 + i] = labels[i] * features[i*64 + a]   (24 KB)
__global__ __launch_bounds__(256) void prep_kernel(
    const float* __restrict__ labels,
    const float* __restrict__ features,
    float* __restrict__ lfT)
{
    int t = blockIdx.x * blockDim.x + threadIdx.x;
    if (t >= NSAMP * NFEAT) return;
    int a = t / NSAMP;     // feature index
    int i = t - a * NSAMP; // sample index
    lfT[t] = labels[i] * features[i * NFEAT + a];
}

__device__ __forceinline__ void solve2x2(
    float a00, float a01, float a10, float a11,
    float li, float lj, float& w0, float& w1)
{
    // Kahan determinant: correct to ~2ulp even when a00*a11 ~ a01*a10
    float p    = a01 * a10;
    float e    = fmaf(a01, a10, -p);           // exact rounding error of p
    float detk = fmaf(a00, a11, -p) + e;

    float fr = fmaf(a11, a11, fmaf(a10, a10, fmaf(a01, a01, a00 * a00)));
    float d2 = detk * detk;
    float rc = RC2F * fr * fr;

    bool full;
    if (d2 > rc * BANDHI) {
        full = true;                            // provably matches f64 test
    } else if (d2 < rc * BANDLO) {
        full = false;                           // provably matches f64 test
    } else {
        // rare band: EXACT f64 test of rounds 1-5 (bit-identical decisions)
        double dA00 = (double)a00, dA01 = (double)a01;
        double dA10 = (double)a10, dA11 = (double)a11;
        double det = dA00 * dA11 - dA01 * dA10;
        double dfr = dA00 * dA00 + dA01 * dA01 + dA10 * dA10 + dA11 * dA11;
        full = det * det > RC2 * (dfr * dfr);
    }

    float y0 = li - 0.1f, y1 = lj - 0.1f;
    if (full) {
        // exact 2x2 inverse, f32 throughout (error budget analysis above)
        float rd   = 1.0f / detk;
        float num0 = fmaf(a11, y0, -(a01 * y1));
        float num1 = fmaf(a00, y1, -(a10 * y0));
        w0 = num0 * rd;
        w1 = num1 * rd;
    } else {
        // rank<=1: truncated pinv ~= A^T y / ||A||_F^2 (rare, values O(1))
        if (fr > 0.0f) {
            float rf = 1.0f / fr;
            w0 = fmaf(a00, y0, a10 * y1) * rf;
            w1 = fmaf(a01, y0, a11 * y1) * rf;
        } else {
            w0 = 0.0f;
            w1 = 0.0f;
        }
    }
}

// grid: (ceil(2280/256)=9, 2016); each thread does sample-pairs s0=2t, 2t+1
// for feature-pair f=blockIdx.y, writing one float4 per output stream.
__global__ __launch_bounds__(256) void rll_kernel(
    const float* __restrict__ labels,     // [96]
    const float* __restrict__ lfT,        // [64][96] transposed label*feature
    const int*   __restrict__ sample_idx, // [4560][2]
    const int*   __restrict__ feat_idx,   // [2016][2]
    float* __restrict__ w_out,            // [TOTAL][2]
    float* __restrict__ c_out)            // [TOTAL][2] (float-encoded ints)
{
    int t = blockIdx.x * blockDim.x + threadIdx.x;   // pair-of-pairs index
    if (t >= MS / 2) return;                          // 2280 threads per f
    int f = blockIdx.y;                               // block-uniform

    int2 ab = ((const int2*)feat_idx)[f];             // scalar load
    const float* __restrict__ rowA = lfT + ab.x * NSAMP;  // SGPR base
    const float* __restrict__ rowB = lfT + ab.y * NSAMP;

    // sample pairs s0=2t and s0+1: one 16B load
    int4 ss = ((const int4*)sample_idx)[t];           // (i0,j0,i1,j1)

    float li0 = labels[ss.x], lj0 = labels[ss.y];
    float w00, w01;
    solve2x2(rowA[ss.x], rowB[ss.x], rowA[ss.y], rowB[ss.y], li0, lj0, w00, w01);
    float li1 = labels[ss.z], lj1 = labels[ss.w];
    float w10, w11;
    solve2x2(rowA[ss.z], rowB[ss.z], rowA[ss.w], rowB[ss.w], li1, lj1, w10, w11);

    size_t q = (size_t)f * (MS / 2) + t;              // float4 index
    f32x4 wv = { w00, w01, w10, w11 };
    __builtin_nontemporal_store(wv, (f32x4*)w_out + q);
    float af = (float)ab.x, bf = (float)ab.y;
    f32x4 cv = { af, bf, af, bf };
    __builtin_nontemporal_store(cv, (f32x4*)c_out + q);
}

extern "C" void kernel_launch(void* const* d_in, const int* in_sizes, int n_in,
                              void* d_out, int out_size, void* d_ws, size_t ws_size,
                              hipStream_t stream) {
    const float* labels     = (const float*)d_in[0];
    const float* features   = (const float*)d_in[1];
    const int*   sample_idx = (const int*)d_in[2];
    const int*   feat_idx   = (const int*)d_in[3];

    float* lfT   = (float*)d_ws;                        // 24 KB scratch
    float* w_out = (float*)d_out;                       // TOTAL*2 floats
    float* c_out = (float*)d_out + (size_t)TOTAL * 2;   // TOTAL*2 floats

    prep_kernel<<<(NSAMP * NFEAT + 255) / 256, 256, 0, stream>>>(
        labels, features, lfT);

    dim3 grid((MS / 2 + 255) / 256, MF);                // (9, 2016)
    rll_kernel<<<grid, 256, 0, stream>>>(labels, lfT, sample_idx,
                                         feat_idx, w_out, c_out);
}